// Round 1
// baseline (530.544 us; speedup 1.0000x reference)
//
#include <hip/hip_runtime.h>

using u16 = unsigned short;
typedef __bf16 bf16x8 __attribute__((ext_vector_type(8)));
typedef float floatx4 __attribute__((ext_vector_type(4)));

// ---------- helpers ----------
__device__ __forceinline__ u16 f2bf(float f) {
    union { float f; unsigned u; } v; v.f = f;
    unsigned r = v.u + 0x7fffu + ((v.u >> 16) & 1u);   // RNE
    return (u16)(r >> 16);
}

__device__ __forceinline__ void gld16(const void* g, void* l) {
    __builtin_amdgcn_global_load_lds(
        (const __attribute__((address_space(1))) void*)g,
        (__attribute__((address_space(3))) void*)l, 16, 0, 0);
}

__device__ __forceinline__ void cvt4(const float* __restrict__ src,
                                     u16* __restrict__ dst, int i) {
    float4 v = *(const float4*)(src + i);
    ushort4 o;
    o.x = f2bf(v.x); o.y = f2bf(v.y); o.z = f2bf(v.z); o.w = f2bf(v.w);
    *(ushort4*)(dst + i) = o;
}

// ---------- prep: converts + time-qkv + bias expansion ----------
// blocks: [0,768) Wqkv cvt | [768,1024) Wo cvt | [1024,1120) time qkv |
//         [1120,1152) bias_full | [1152,9344) x cvt
__global__ __launch_bounds__(256) void prep_k(
    const float* __restrict__ x, const float* __restrict__ Wqkv,
    const float* __restrict__ Wo, const float* __restrict__ te,
    const float* __restrict__ Wt, const float* __restrict__ bt,
    const float* __restrict__ btab,
    u16* __restrict__ xbf, u16* __restrict__ wqkvbf, u16* __restrict__ wobf,
    float* __restrict__ qkvt, float* __restrict__ biasf)
{
    const int b = blockIdx.x, tid = threadIdx.x;
    if (b < 768) {
        cvt4(Wqkv, wqkvbf, b * 1024 + tid * 4);
    } else if (b < 1024) {
        cvt4(Wo, wobf, (b - 768) * 1024 + tid * 4);
    } else if (b < 1120) {
        const int bb = b - 1024;
        const int batch = bb / 6;
        const int c = (bb % 6) * 256 + tid;
        const float4* a4 = (const float4*)(te + batch * 512);
        const float4* w4 = (const float4*)(Wt + (size_t)c * 512);
        float s = 0.f;
        for (int i = 0; i < 128; ++i) {
            float4 av = a4[i], wv = w4[i];
            s += av.x * wv.x + av.y * wv.y + av.z * wv.z + av.w * wv.w;
        }
        qkvt[batch * 1536 + c] = s + bt[c];
    } else if (b < 1152) {
        const int e0 = (b - 1120) * 1024 + tid;
        for (int k = 0; k < 4; ++k) {
            int e = e0 + k * 256;
            int h = e >> 12, rc = e & 4095, row = rc >> 6, col = rc & 63;
            int idx = ((row >> 3) - (col >> 3) + 7) * 15 + ((row & 7) - (col & 7) + 7);
            biasf[e] = btab[idx * 8 + h];
        }
    } else {
        const int base = (b - 1152) * 4096 + tid * 4;
        for (int k = 0; k < 4; ++k) cvt4(x, xbf, base + k * 1024);
    }
}

// ---------- GEMM1: qkv = x @ Wqkv^T + bqkv + qkv_t[batch], bf16 out ----------
// 256x256 tile, BK=64, 8 waves (2M x 4N), 8-phase schedule:
//   T2 XOR-swizzled LDS (linear gld16 dest + inverse-swizzled global src),
//   T3/T4 counted vmcnt(2) at phases 4/8 only, T5 setprio around MFMA clusters,
//   T1 bijective XCD swizzle (1536 blocks % 8 == 0).
#define MMQ(MB, NB, BF)                                                        \
  _Pragma("unroll") for (int i_ = 0; i_ < 4; ++i_) {                           \
    _Pragma("unroll") for (int j_ = 0; j_ < 2; ++j_) {                         \
      acc[MB + i_][NB + j_] = __builtin_amdgcn_mfma_f32_16x16x32_bf16(         \
          afr[i_][0], BF[j_][0], acc[MB + i_][NB + j_], 0, 0, 0);              \
      acc[MB + i_][NB + j_] = __builtin_amdgcn_mfma_f32_16x16x32_bf16(         \
          afr[i_][1], BF[j_][1], acc[MB + i_][NB + j_], 0, 0, 0);              \
    }                                                                          \
  }

#define PHASES_TILE(BUF, S0, LASTIT)                                           \
  /* PH1: A m0-3 + B n0-1 (12 ds_reads), quadrant (m0-3, n0-1) */              \
  LDA4(BUF, 0); LDB2(BUF, bf0, 0);                                             \
  STAGE(S0 + 0);                                                               \
  __builtin_amdgcn_s_barrier();                                                \
  asm volatile("s_waitcnt lgkmcnt(0)" ::: "memory");                           \
  __builtin_amdgcn_s_setprio(1);                                               \
  MMQ(0, 0, bf0);                                                              \
  __builtin_amdgcn_s_setprio(0);                                               \
  __builtin_amdgcn_s_barrier();                                                \
  /* PH2: B n2-3 (4 ds_reads), quadrant (m0-3, n2-3) */                        \
  LDB2(BUF, bf1, 2);                                                           \
  STAGE(S0 + 1);                                                               \
  __builtin_amdgcn_s_barrier();                                                \
  asm volatile("s_waitcnt lgkmcnt(0)" ::: "memory");                           \
  __builtin_amdgcn_s_setprio(1);                                               \
  MMQ(0, 2, bf1);                                                              \
  __builtin_amdgcn_s_setprio(0);                                               \
  __builtin_amdgcn_s_barrier();                                                \
  /* PH3: A m4-7 (8 ds_reads), quadrant (m4-7, n2-3) */                        \
  LDA4(BUF, 4);                                                                \
  STAGE(S0 + 2);                                                               \
  __builtin_amdgcn_s_barrier();                                                \
  asm volatile("s_waitcnt lgkmcnt(0)" ::: "memory");                           \
  __builtin_amdgcn_s_setprio(1);                                               \
  MMQ(4, 2, bf1);                                                              \
  __builtin_amdgcn_s_setprio(0);                                               \
  __builtin_amdgcn_s_barrier();                                                \
  /* PH4: no ds_reads, quadrant (m4-7, n0-1); counted vmcnt */                 \
  STAGE(S0 + 3);                                                               \
  __builtin_amdgcn_s_barrier();                                                \
  __builtin_amdgcn_s_setprio(1);                                               \
  MMQ(4, 0, bf0);                                                              \
  __builtin_amdgcn_s_setprio(0);                                               \
  if (LASTIT) { asm volatile("s_waitcnt vmcnt(0)" ::: "memory"); }             \
  else        { asm volatile("s_waitcnt vmcnt(2)" ::: "memory"); }             \
  __builtin_amdgcn_s_barrier();

__global__ __launch_bounds__(512, 1) void gemm_qkv_k(
    const u16* __restrict__ A, const u16* __restrict__ B,
    const float* __restrict__ bqkv, const float* __restrict__ qkvt,
    u16* __restrict__ C)
{
    __shared__ __align__(16) u16 lA[2 * 256 * 64];   // 64 KiB, [buf][256][64]
    __shared__ __align__(16) u16 lB[2 * 256 * 64];   // 64 KiB
    const int tid = threadIdx.x;
    const int lane = tid & 63, wv = tid >> 6;
    const int ln = lane & 15, quad = lane >> 4;

    // T1: bijective XCD swizzle over 1536 blocks (1536 % 8 == 0)
    const int orig = blockIdx.y * 6 + blockIdx.x;
    const int wgid = (orig & 7) * 192 + (orig >> 3);
    const int tm = wgid / 6, tn = wgid % 6;

    const int wm = (wv >> 2) * 128;          // 2 M-waves
    const int wn = (wv & 3) * 64;            // 4 N-waves

    const u16* ag = A + (size_t)tm * 256 * 512;
    const u16* bg = B + (size_t)tn * 256 * 512;

    floatx4 acc[8][4];
#pragma unroll
    for (int i = 0; i < 8; ++i)
#pragma unroll
        for (int j = 0; j < 4; ++j) acc[i][j] = (floatx4){0.f, 0.f, 0.f, 0.f};

    bf16x8 afr[4][2];       // current A m-quadrant (reloaded per half-tile)
    bf16x8 bf0[2][2];       // B n0-1, live across the whole K-tile
    bf16x8 bf1[2][2];       // B n2-3

    // stage one half-tile (16 KiB): sidx = 4*tile + {0:A-lo,1:A-hi,2:B-lo,3:B-hi}
    // linear LDS dest (= base + tid*16B), inverse-swizzled global source (rule 21)
    auto STAGE = [&](int sidx) {
        if (sidx >= 32) return;              // 8 K-tiles only
        const int h = sidx & 3, ts = sidx >> 2;
        const u16* g = (h < 2) ? ag : bg;
        u16* lb = ((h < 2) ? lA : lB) + (ts & 1) * (256 * 64);
        const int r0 = (h & 1) * 128;
        const int k0 = ts * 64;
#pragma unroll
        for (int rnd = 0; rnd < 2; ++rnd) {
            const int r = r0 + rnd * 64 + (tid >> 3);
            const int cb = ((tid & 7) * 16) ^ ((r & 7) << 4);   // swizzled src col
            gld16(g + (size_t)r * 512 + k0 + (cb >> 1),
                  lb + r * 64 + (tid & 7) * 8);
        }
    };

    auto LDA4 = [&](int buf, int mb) {       // A frags mt=mb..mb+3, kk=0,1
#pragma unroll
        for (int i = 0; i < 4; ++i) {
            const int r = wm + (mb + i) * 16 + ln;
            const int sw = (r & 7) << 4;
            const char* p = (const char*)(lA + buf * (256 * 64)) + r * 128;
            afr[i][0] = *(const bf16x8*)(p + ((quad * 16) ^ sw));
            afr[i][1] = *(const bf16x8*)(p + ((64 + quad * 16) ^ sw));
        }
    };
    auto LDB2 = [&](int buf, bf16x8 (&bfr)[2][2], int nb) {  // B frags nt=nb..nb+1
#pragma unroll
        for (int j = 0; j < 2; ++j) {
            const int r = wn + (nb + j) * 16 + ln;
            const int sw = (r & 7) << 4;
            const char* p = (const char*)(lB + buf * (256 * 64)) + r * 128;
            bfr[j][0] = *(const bf16x8*)(p + ((quad * 16) ^ sw));
            bfr[j][1] = *(const bf16x8*)(p + ((64 + quad * 16) ^ sw));
        }
    };

    // prologue: tile0 fully + A-lo of tile1 in flight (10 loads, wait oldest 8)
    STAGE(0); STAGE(1); STAGE(2); STAGE(3); STAGE(4);
    asm volatile("s_waitcnt vmcnt(2)" ::: "memory");
    __builtin_amdgcn_s_barrier();

    int sidx = 5;
    for (int it = 0; it < 4; ++it) {
        const bool last = (it == 3);
        PHASES_TILE(0, sidx + 0, last);      // K-tile 2*it   (buf0), phases 1-4
        PHASES_TILE(1, sidx + 4, last);      // K-tile 2*it+1 (buf1), phases 5-8
        sidx += 8;
    }

    // epilogue: C = acc + bqkv + time-qkv (batch uniform per 256-row tile)
    const float* qt = qkvt + (tm >> 4) * 1536;
#pragma unroll
    for (int nt = 0; nt < 4; ++nt) {
        const int col = tn * 256 + wn + nt * 16 + ln;
        const float add = bqkv[col] + qt[col];
#pragma unroll
        for (int mt = 0; mt < 8; ++mt) {
            const int row0 = tm * 256 + wm + mt * 16 + quad * 4;
#pragma unroll
            for (int r = 0; r < 4; ++r)
                C[(size_t)(row0 + r) * 1536 + col] = f2bf(acc[mt][nt][r] + add);
        }
    }
}

// ---------- attention: one wave per (window, head) ----------
__global__ __launch_bounds__(256, 2) void attn_k(
    const u16* __restrict__ qkv, const float* __restrict__ biasf,
    u16* __restrict__ aout)
{
    __shared__ __align__(16) u16 vt[4][64 * 72];   // V^T per wave: [d][n]
    __shared__ __align__(16) u16 pl[4][64 * 72];   // P per wave:   [m][n]
    const int tid = threadIdx.x, lane = tid & 63, wv = tid >> 6;
    const int ln = lane & 15, quad = lane >> 4;
    const int pair = blockIdx.x * 4 + wv;
    const int w = pair >> 3, h = pair & 7;
    const int bb = w >> 6, nh = (w >> 3) & 7, nw = w & 7;
    const int tbase = bb * 4096 + nh * 512 + nw * 8;  // + wi*64 + wj
    u16* vtw = vt[wv];
    u16* plw = pl[wv];

    // ---- V load (coalesced rows) + transpose into LDS ----
    {
        const int wj = lane >> 3;           // 0..7
        const int d0 = (lane & 7) * 8;      // 0..56
#pragma unroll
        for (int i = 0; i < 8; ++i) {
            const int t = tbase + i * 64 + wj;     // token of n = i*8+wj
            union { bf16x8 v; u16 u[8]; } cv;
            cv.v = *(const bf16x8*)(qkv + (size_t)t * 1536 + 1024 + h * 64 + d0);
            const int n = i * 8 + wj;
#pragma unroll
            for (int j = 0; j < 8; ++j) vtw[(d0 + j) * 72 + n] = cv.u[j];
        }
    }

    // ---- K fragments (B-operand layout, straight from global) ----
    bf16x8 kf[4][2];
#pragma unroll
    for (int nt = 0; nt < 4; ++nt) {
        const int n = nt * 16 + ln;
        const int t = tbase + (n >> 3) * 64 + (n & 7);
        const u16* kr = qkv + (size_t)t * 1536 + 512 + h * 64 + quad * 8;
        kf[nt][0] = *(const bf16x8*)kr;
        kf[nt][1] = *(const bf16x8*)(kr + 32);
    }

    // ---- S = Q K^T * scale + bias, softmax, write P (bf16) to LDS ----
#pragma unroll
    for (int mt = 0; mt < 4; ++mt) {
        const int m = mt * 16 + ln;
        const int t = tbase + (m >> 3) * 64 + (m & 7);
        const u16* qr = qkv + (size_t)t * 1536 + h * 64 + quad * 8;
        const bf16x8 qf0 = *(const bf16x8*)qr;
        const bf16x8 qf1 = *(const bf16x8*)(qr + 32);
        floatx4 s[4];
#pragma unroll
        for (int nt = 0; nt < 4; ++nt) {
            s[nt] = (floatx4){0.f, 0.f, 0.f, 0.f};
            s[nt] = __builtin_amdgcn_mfma_f32_16x16x32_bf16(qf0, kf[nt][0], s[nt], 0, 0, 0);
            s[nt] = __builtin_amdgcn_mfma_f32_16x16x32_bf16(qf1, kf[nt][1], s[nt], 0, 0, 0);
        }
        float z[4][4];
        const float* bptr = biasf + h * 4096 + (mt * 16 + quad * 4) * 64 + ln;
#pragma unroll
        for (int nt = 0; nt < 4; ++nt)
#pragma unroll
            for (int r = 0; r < 4; ++r)
                z[nt][r] = s[nt][r] * 0.125f + bptr[r * 64 + nt * 16];
        float pmax[4], prcp[4];
#pragma unroll
        for (int r = 0; r < 4; ++r) {
            float v = fmaxf(fmaxf(z[0][r], z[1][r]), fmaxf(z[2][r], z[3][r]));
            v = fmaxf(v, __shfl_xor(v, 1));
            v = fmaxf(v, __shfl_xor(v, 2));
            v = fmaxf(v, __shfl_xor(v, 4));
            v = fmaxf(v, __shfl_xor(v, 8));
            pmax[r] = v;
        }
#pragma unroll
        for (int nt = 0; nt < 4; ++nt)
#pragma unroll
            for (int r = 0; r < 4; ++r)
                z[nt][r] = __expf(z[nt][r] - pmax[r]);
#pragma unroll
        for (int r = 0; r < 4; ++r) {
            float v = z[0][r] + z[1][r] + z[2][r] + z[3][r];
            v += __shfl_xor(v, 1);
            v += __shfl_xor(v, 2);
            v += __shfl_xor(v, 4);
            v += __shfl_xor(v, 8);
            prcp[r] = __builtin_amdgcn_rcpf(v);
        }
#pragma unroll
        for (int nt = 0; nt < 4; ++nt)
#pragma unroll
            for (int r = 0; r < 4; ++r)
                plw[(mt * 16 + quad * 4 + r) * 72 + nt * 16 + ln] =
                    f2bf(z[nt][r] * prcp[r]);
    }

    __syncthreads();   // order LDS writes (vt, pl) before typed re-reads below

    // ---- O = P @ V : A-op from pl, B-op from vt (V^T rows) ----
    bf16x8 vtf[4][2];
#pragma unroll
    for (int dt = 0; dt < 4; ++dt) {
        const u16* vr = &vtw[(dt * 16 + ln) * 72 + quad * 8];
        vtf[dt][0] = *(const bf16x8*)vr;
        vtf[dt][1] = *(const bf16x8*)(vr + 32);
    }
#pragma unroll
    for (int mt = 0; mt < 4; ++mt) {
        const u16* pr = &plw[(mt * 16 + ln) * 72 + quad * 8];
        const bf16x8 pf0 = *(const bf16x8*)pr;
        const bf16x8 pf1 = *(const bf16x8*)(pr + 32);
#pragma unroll
        for (int dt = 0; dt < 4; ++dt) {
            floatx4 o = (floatx4){0.f, 0.f, 0.f, 0.f};
            o = __builtin_amdgcn_mfma_f32_16x16x32_bf16(pf0, vtf[dt][0], o, 0, 0, 0);
            o = __builtin_amdgcn_mfma_f32_16x16x32_bf16(pf1, vtf[dt][1], o, 0, 0, 0);
            const size_t rbase =
                (size_t)(w * 64 + mt * 16 + quad * 4) * 512 + h * 64 + dt * 16 + ln;
#pragma unroll
            for (int r = 0; r < 4; ++r)
                aout[rbase + (size_t)r * 512] = f2bf(o[r]);
        }
    }
}

// ---------- GEMM2: out = attn @ Wo^T + bo, fp32 out ----------
__global__ __launch_bounds__(256, 3) void gemm_out_k(
    const u16* __restrict__ A, const u16* __restrict__ B,
    const float* __restrict__ bo, float* __restrict__ C)
{
    __shared__ __align__(16) u16 lA[128 * 32];
    __shared__ __align__(16) u16 lB[128 * 32];
    const int tid = threadIdx.x;
    const int lane = tid & 63, wv = tid >> 6;
    const int ln = lane & 15, quad = lane >> 4;
    const int tn = blockIdx.x, tm = blockIdx.y;
    const int wm = (wv & 1) * 64, wn = (wv >> 1) * 64;

    floatx4 acc[4][4];
#pragma unroll
    for (int i = 0; i < 4; ++i)
#pragma unroll
        for (int j = 0; j < 4; ++j) acc[i][j] = (floatx4){0.f, 0.f, 0.f, 0.f};

    const int srow = tid >> 2, scb = tid & 3;
    const u16* ag = A + (size_t)(tm * 128 + srow) * 512 + scb * 8;
    const u16* bg = B + (size_t)(tn * 128 + srow) * 512 + scb * 8;
    u16* la0 = &lA[tid * 8];
    u16* la1 = &lA[2048 + tid * 8];
    u16* lb0 = &lB[tid * 8];
    u16* lb1 = &lB[2048 + tid * 8];

    for (int k0 = 0; k0 < 512; k0 += 32) {
        __syncthreads();
        gld16(ag + k0, la0);
        gld16(ag + 64 * 512 + k0, la1);
        gld16(bg + k0, lb0);
        gld16(bg + 64 * 512 + k0, lb1);
        __syncthreads();
        bf16x8 af[4], bf[4];
#pragma unroll
        for (int mt = 0; mt < 4; ++mt)
            af[mt] = *(const bf16x8*)&lA[(wm + mt * 16 + ln) * 32 + quad * 8];
#pragma unroll
        for (int nt = 0; nt < 4; ++nt)
            bf[nt] = *(const bf16x8*)&lB[(wn + nt * 16 + ln) * 32 + quad * 8];
#pragma unroll
        for (int mt = 0; mt < 4; ++mt)
#pragma unroll
            for (int nt = 0; nt < 4; ++nt)
                acc[mt][nt] = __builtin_amdgcn_mfma_f32_16x16x32_bf16(
                    af[mt], bf[nt], acc[mt][nt], 0, 0, 0);
    }

#pragma unroll
    for (int nt = 0; nt < 4; ++nt) {
        const int col = tn * 128 + wn + nt * 16 + ln;
        const float add = bo[col];
#pragma unroll
        for (int mt = 0; mt < 4; ++mt) {
            const int row0 = tm * 128 + wm + mt * 16 + quad * 4;
#pragma unroll
            for (int r = 0; r < 4; ++r)
                C[(size_t)(row0 + r) * 512 + col] = acc[mt][nt][r] + add;
        }
    }
}

// ---------- launch ----------
extern "C" void kernel_launch(void* const* d_in, const int* in_sizes, int n_in,
                              void* d_out, int out_size, void* d_ws, size_t ws_size,
                              hipStream_t stream)
{
    const float* x    = (const float*)d_in[0];
    const float* te   = (const float*)d_in[1];
    const float* Wqkv = (const float*)d_in[2];
    const float* bqkv = (const float*)d_in[3];
    const float* Wt   = (const float*)d_in[4];
    const float* bt   = (const float*)d_in[5];
    const float* Wo   = (const float*)d_in[6];
    const float* bo   = (const float*)d_in[7];
    const float* btab = (const float*)d_in[8];
    float* out = (float*)d_out;

    char* w = (char*)d_ws;
    // x_bf (later reused as attn_out): 67,108,864 B
    u16*   xbf    = (u16*)(w);
    u16*   qkvbf  = (u16*)(w + 67108864);        // 201,326,592 B
    u16*   wqkvbf = (u16*)(w + 268435456);       // 1,572,864 B
    u16*   wobf   = (u16*)(w + 270008320);       // 524,288 B
    float* qkvt   = (float*)(w + 270532608);     // 98,304 B
    float* biasf  = (float*)(w + 270630912);     // 131,072 B  (total ~258.2 MiB)

    prep_k<<<9344, 256, 0, stream>>>(x, Wqkv, Wo, te, Wt, bt, btab,
                                     xbf, wqkvbf, wobf, qkvt, biasf);
    gemm_qkv_k<<<dim3(6, 256), 512, 0, stream>>>(xbf, wqkvbf, bqkv, qkvt, qkvbf);
    attn_k<<<2048, 256, 0, stream>>>(qkvbf, biasf, xbf /* reuse as attn_out */);
    gemm_out_k<<<dim3(4, 512), 256, 0, stream>>>(xbf, wobf, bo, out);
}

// Round 2
// 506.298 us; speedup vs baseline: 1.0479x; 1.0479x over previous
//
#include <hip/hip_runtime.h>

using u16 = unsigned short;
typedef __bf16 bf16x8 __attribute__((ext_vector_type(8)));
typedef float floatx4 __attribute__((ext_vector_type(4)));

// ---------- helpers ----------
__device__ __forceinline__ u16 f2bf(float f) {
    union { float f; unsigned u; } v; v.f = f;
    unsigned r = v.u + 0x7fffu + ((v.u >> 16) & 1u);   // RNE
    return (u16)(r >> 16);
}

__device__ __forceinline__ void gld16(const void* g, void* l) {
    __builtin_amdgcn_global_load_lds(
        (const __attribute__((address_space(1))) void*)g,
        (__attribute__((address_space(3))) void*)l, 16, 0, 0);
}

__device__ __forceinline__ void cvt4(const float* __restrict__ src,
                                     u16* __restrict__ dst, int i) {
    float4 v = *(const float4*)(src + i);
    ushort4 o;
    o.x = f2bf(v.x); o.y = f2bf(v.y); o.z = f2bf(v.z); o.w = f2bf(v.w);
    *(ushort4*)(dst + i) = o;
}

// ---------- prep: weight converts + time-qkv + bias expansion ----------
// blocks: [0,768) Wqkv cvt | [768,1024) Wo cvt | [1024,1120) time qkv |
//         [1120,1152) bias_full
__global__ __launch_bounds__(256) void prep_k(
    const float* __restrict__ Wqkv, const float* __restrict__ Wo,
    const float* __restrict__ te, const float* __restrict__ Wt,
    const float* __restrict__ bt, const float* __restrict__ btab,
    u16* __restrict__ wqkvbf, u16* __restrict__ wobf,
    float* __restrict__ qkvt, float* __restrict__ biasf)
{
    const int b = blockIdx.x, tid = threadIdx.x;
    if (b < 768) {
        cvt4(Wqkv, wqkvbf, b * 1024 + tid * 4);
    } else if (b < 1024) {
        cvt4(Wo, wobf, (b - 768) * 1024 + tid * 4);
    } else if (b < 1120) {
        const int bb = b - 1024;
        const int batch = bb / 6;
        const int c = (bb % 6) * 256 + tid;
        const float4* a4 = (const float4*)(te + batch * 512);
        const float4* w4 = (const float4*)(Wt + (size_t)c * 512);
        float s = 0.f;
        for (int i = 0; i < 128; ++i) {
            float4 av = a4[i], wv = w4[i];
            s += av.x * wv.x + av.y * wv.y + av.z * wv.z + av.w * wv.w;
        }
        qkvt[batch * 1536 + c] = s + bt[c];
    } else {
        const int e0 = (b - 1120) * 1024 + tid;
        for (int k = 0; k < 4; ++k) {
            int e = e0 + k * 256;
            int h = e >> 12, rc = e & 4095, row = rc >> 6, col = rc & 63;
            int idx = ((row >> 3) - (col >> 3) + 7) * 15 + ((row & 7) - (col & 7) + 7);
            biasf[e] = btab[idx * 8 + h];
        }
    }
}

// ---------- fused: x-cvt + qkv GEMM + windowed attention ----------
// block = 1 window (64 tokens), 512 threads = 8 waves = 8 heads.
// x window staged once to LDS (bf16, pad-520 rows: 2-way-free bank pattern).
// Per wave: q/k/v 64x64x512 GEMMs (A from LDS, B from L2-resident wqkvbf),
// C-layout -> per-wave LDS buf roundtrips for fragment relayout (attn_k-proven),
// V^T frags hoisted to regs before P overwrites the single per-wave buffer.

#define GEMM64(CB)                                                             \
  _Pragma("unroll") for (int i_ = 0; i_ < 4; ++i_)                             \
    _Pragma("unroll") for (int j_ = 0; j_ < 4; ++j_)                           \
      acc[i_][j_] = (floatx4){0.f, 0.f, 0.f, 0.f};                             \
  _Pragma("unroll 2") for (int ks = 0; ks < 16; ++ks) {                        \
    bf16x8 af_[4], bw_[4];                                                     \
    _Pragma("unroll") for (int mt = 0; mt < 4; ++mt)                           \
      af_[mt] = *(const bf16x8*)&xw[(mt * 16 + ln) * 520 + ks * 32 + quad * 8];\
    _Pragma("unroll") for (int nt = 0; nt < 4; ++nt)                           \
      bw_[nt] = *(const bf16x8*)(wqkv +                                        \
          (size_t)((CB) + nt * 16 + ln) * 512 + ks * 32 + quad * 8);           \
    _Pragma("unroll") for (int mt = 0; mt < 4; ++mt)                           \
      _Pragma("unroll") for (int nt = 0; nt < 4; ++nt)                         \
        acc[mt][nt] = __builtin_amdgcn_mfma_f32_16x16x32_bf16(                 \
            af_[mt], bw_[nt], acc[mt][nt], 0, 0, 0);                           \
  }

// write acc (+bias+time) to buf as [token][d]
#define WRN(CB)                                                                \
  _Pragma("unroll") for (int nt = 0; nt < 4; ++nt) {                           \
    const int col_ = (CB) + nt * 16 + ln;                                      \
    const float add_ = bqkv[col_] + qtv[col_];                                 \
    _Pragma("unroll") for (int mt = 0; mt < 4; ++mt)                           \
      _Pragma("unroll") for (int r = 0; r < 4; ++r)                            \
        buf[(mt * 16 + quad * 4 + r) * 72 + nt * 16 + ln] =                    \
            f2bf(acc[mt][nt][r] + add_);                                       \
  }

// write acc (+bias+time) to buf transposed: [d][token]  (V^T)
#define WRT(CB)                                                                \
  _Pragma("unroll") for (int nt = 0; nt < 4; ++nt) {                           \
    const int col_ = (CB) + nt * 16 + ln;                                      \
    const float add_ = bqkv[col_] + qtv[col_];                                 \
    _Pragma("unroll") for (int mt = 0; mt < 4; ++mt)                           \
      _Pragma("unroll") for (int r = 0; r < 4; ++r)                            \
        buf[(nt * 16 + ln) * 72 + mt * 16 + quad * 4 + r] =                    \
            f2bf(acc[mt][nt][r] + add_);                                       \
  }

// read 4x2 fragments from buf rows [i*16+ln], k-elems kk*32+quad*8
#define RDF(DST)                                                               \
  _Pragma("unroll") for (int i_ = 0; i_ < 4; ++i_) {                           \
    const u16* p_ = &buf[(i_ * 16 + ln) * 72 + quad * 8];                      \
    DST[i_][0] = *(const bf16x8*)p_;                                           \
    DST[i_][1] = *(const bf16x8*)(p_ + 32);                                    \
  }

__global__ __launch_bounds__(512, 2) void fused_k(
    const float* __restrict__ x, const u16* __restrict__ wqkv,
    const float* __restrict__ bqkv, const float* __restrict__ qkvt,
    const float* __restrict__ biasf, u16* __restrict__ aout)
{
    __shared__ __align__(16) u16 xw[64 * 520];       // 66,560 B
    __shared__ __align__(16) u16 sbuf[8][64 * 72];   // 73,728 B
    const int tid = threadIdx.x, lane = tid & 63, wv = tid >> 6;
    const int ln = lane & 15, quad = lane >> 4;
    const int w = blockIdx.x;
    const int bb = w >> 6, nh = (w >> 3) & 7, nw = w & 7;
    const int tbase = bb * 4096 + nh * 512 + nw * 8;  // + wi*64 + wj
    const int h = wv;
    u16* buf = sbuf[wv];
    const float* qtv = qkvt + bb * 1536;

    // ---- stage x window -> bf16 LDS [64][520] ----
    {
        const int t = tid >> 3, cc = tid & 7;
        const int g = tbase + (t >> 3) * 64 + (t & 7);
        const float* xr = x + (size_t)g * 512;
        u16* dst = &xw[t * 520];
#pragma unroll
        for (int c = 0; c < 8; ++c) {
            const int col = cc * 8 + c * 64;
            float4 a = *(const float4*)(xr + col);
            float4 bvec = *(const float4*)(xr + col + 4);
            ushort4 lo, hi;
            lo.x = f2bf(a.x); lo.y = f2bf(a.y); lo.z = f2bf(a.z); lo.w = f2bf(a.w);
            hi.x = f2bf(bvec.x); hi.y = f2bf(bvec.y); hi.z = f2bf(bvec.z); hi.w = f2bf(bvec.w);
            *(ushort4*)(dst + col) = lo;
            *(ushort4*)(dst + col + 4) = hi;
        }
    }
    __syncthreads();   // xw ready; afterwards waves are fully independent

    floatx4 acc[4][4];
    bf16x8 qf[4][2], kf[4][2], vtf[4][2];

    // ---- Q = xw @ Wqkv[h*64..)^T + bqkv + qkvt ----
    GEMM64(h * 64);
    WRN(h * 64);
    RDF(qf);                       // A-frags: rows = q-tokens

    // ---- K ----
    GEMM64(512 + h * 64);
    WRN(512 + h * 64);
    RDF(kf);                       // B-frags: rows = kv-tokens

    // ---- V (transposed store) ----
    GEMM64(1024 + h * 64);
    WRT(1024 + h * 64);
    RDF(vtf);                      // B-frags from V^T rows = d; regs hoisted
                                   // before P overwrites buf below

    // ---- S = Q K^T * scale + bias, softmax, P -> buf (bf16) ----
#pragma unroll
    for (int mt = 0; mt < 4; ++mt) {
        floatx4 s[4];
#pragma unroll
        for (int nt = 0; nt < 4; ++nt) {
            s[nt] = (floatx4){0.f, 0.f, 0.f, 0.f};
            s[nt] = __builtin_amdgcn_mfma_f32_16x16x32_bf16(qf[mt][0], kf[nt][0], s[nt], 0, 0, 0);
            s[nt] = __builtin_amdgcn_mfma_f32_16x16x32_bf16(qf[mt][1], kf[nt][1], s[nt], 0, 0, 0);
        }
        float z[4][4];
        const float* bptr = biasf + h * 4096 + (mt * 16 + quad * 4) * 64 + ln;
#pragma unroll
        for (int nt = 0; nt < 4; ++nt)
#pragma unroll
            for (int r = 0; r < 4; ++r)
                z[nt][r] = s[nt][r] * 0.125f + bptr[r * 64 + nt * 16];
        float pmax[4], prcp[4];
#pragma unroll
        for (int r = 0; r < 4; ++r) {
            float v = fmaxf(fmaxf(z[0][r], z[1][r]), fmaxf(z[2][r], z[3][r]));
            v = fmaxf(v, __shfl_xor(v, 1));
            v = fmaxf(v, __shfl_xor(v, 2));
            v = fmaxf(v, __shfl_xor(v, 4));
            v = fmaxf(v, __shfl_xor(v, 8));
            pmax[r] = v;
        }
#pragma unroll
        for (int nt = 0; nt < 4; ++nt)
#pragma unroll
            for (int r = 0; r < 4; ++r)
                z[nt][r] = __expf(z[nt][r] - pmax[r]);
#pragma unroll
        for (int r = 0; r < 4; ++r) {
            float v = z[0][r] + z[1][r] + z[2][r] + z[3][r];
            v += __shfl_xor(v, 1);
            v += __shfl_xor(v, 2);
            v += __shfl_xor(v, 4);
            v += __shfl_xor(v, 8);
            prcp[r] = __builtin_amdgcn_rcpf(v);
        }
#pragma unroll
        for (int nt = 0; nt < 4; ++nt)
#pragma unroll
            for (int r = 0; r < 4; ++r)
                buf[(mt * 16 + quad * 4 + r) * 72 + nt * 16 + ln] =
                    f2bf(z[nt][r] * prcp[r]);
    }

    // ---- O = P @ V : A-op from buf (P), B-op from vtf regs ----
#pragma unroll
    for (int mt = 0; mt < 4; ++mt) {
        const u16* pr = &buf[(mt * 16 + ln) * 72 + quad * 8];
        const bf16x8 pf0 = *(const bf16x8*)pr;
        const bf16x8 pf1 = *(const bf16x8*)(pr + 32);
#pragma unroll
        for (int dt = 0; dt < 4; ++dt) {
            floatx4 o = (floatx4){0.f, 0.f, 0.f, 0.f};
            o = __builtin_amdgcn_mfma_f32_16x16x32_bf16(pf0, vtf[dt][0], o, 0, 0, 0);
            o = __builtin_amdgcn_mfma_f32_16x16x32_bf16(pf1, vtf[dt][1], o, 0, 0, 0);
            const size_t rbase =
                (size_t)(w * 64 + mt * 16 + quad * 4) * 512 + h * 64 + dt * 16 + ln;
#pragma unroll
            for (int r = 0; r < 4; ++r)
                aout[rbase + (size_t)r * 512] = f2bf(o[r]);
        }
    }
}

// ---------- GEMM2: out = attn @ Wo^T + bo, fp32 out ----------
__global__ __launch_bounds__(256, 3) void gemm_out_k(
    const u16* __restrict__ A, const u16* __restrict__ B,
    const float* __restrict__ bo, float* __restrict__ C)
{
    __shared__ __align__(16) u16 lA[128 * 32];
    __shared__ __align__(16) u16 lB[128 * 32];
    const int tid = threadIdx.x;
    const int lane = tid & 63, wv = tid >> 6;
    const int ln = lane & 15, quad = lane >> 4;
    const int tn = blockIdx.x, tm = blockIdx.y;
    const int wm = (wv & 1) * 64, wn = (wv >> 1) * 64;

    floatx4 acc[4][4];
#pragma unroll
    for (int i = 0; i < 4; ++i)
#pragma unroll
        for (int j = 0; j < 4; ++j) acc[i][j] = (floatx4){0.f, 0.f, 0.f, 0.f};

    const int srow = tid >> 2, scb = tid & 3;
    const u16* ag = A + (size_t)(tm * 128 + srow) * 512 + scb * 8;
    const u16* bg = B + (size_t)(tn * 128 + srow) * 512 + scb * 8;
    u16* la0 = &lA[tid * 8];
    u16* la1 = &lA[2048 + tid * 8];
    u16* lb0 = &lB[tid * 8];
    u16* lb1 = &lB[2048 + tid * 8];

    for (int k0 = 0; k0 < 512; k0 += 32) {
        __syncthreads();
        gld16(ag + k0, la0);
        gld16(ag + 64 * 512 + k0, la1);
        gld16(bg + k0, lb0);
        gld16(bg + 64 * 512 + k0, lb1);
        __syncthreads();
        bf16x8 af[4], bf[4];
#pragma unroll
        for (int mt = 0; mt < 4; ++mt)
            af[mt] = *(const bf16x8*)&lA[(wm + mt * 16 + ln) * 32 + quad * 8];
#pragma unroll
        for (int nt = 0; nt < 4; ++nt)
            bf[nt] = *(const bf16x8*)&lB[(wn + nt * 16 + ln) * 32 + quad * 8];
#pragma unroll
        for (int mt = 0; mt < 4; ++mt)
#pragma unroll
            for (int nt = 0; nt < 4; ++nt)
                acc[mt][nt] = __builtin_amdgcn_mfma_f32_16x16x32_bf16(
                    af[mt], bf[nt], acc[mt][nt], 0, 0, 0);
    }

#pragma unroll
    for (int nt = 0; nt < 4; ++nt) {
        const int col = tn * 128 + wn + nt * 16 + ln;
        const float add = bo[col];
#pragma unroll
        for (int mt = 0; mt < 4; ++mt) {
            const int row0 = tm * 128 + wm + mt * 16 + quad * 4;
#pragma unroll
            for (int r = 0; r < 4; ++r)
                C[(size_t)(row0 + r) * 512 + col] = acc[mt][nt][r] + add;
        }
    }
}

// ---------- launch ----------
extern "C" void kernel_launch(void* const* d_in, const int* in_sizes, int n_in,
                              void* d_out, int out_size, void* d_ws, size_t ws_size,
                              hipStream_t stream)
{
    const float* x    = (const float*)d_in[0];
    const float* te   = (const float*)d_in[1];
    const float* Wqkv = (const float*)d_in[2];
    const float* bqkv = (const float*)d_in[3];
    const float* Wt   = (const float*)d_in[4];
    const float* bt   = (const float*)d_in[5];
    const float* Wo   = (const float*)d_in[6];
    const float* bo   = (const float*)d_in[7];
    const float* btab = (const float*)d_in[8];
    float* out = (float*)d_out;

    char* w = (char*)d_ws;
    u16*   aoutbf = (u16*)(w);                   // attn out: 67,108,864 B
    u16*   wqkvbf = (u16*)(w + 268435456);       // 1,572,864 B
    u16*   wobf   = (u16*)(w + 270008320);       // 524,288 B
    float* qkvt   = (float*)(w + 270532608);     // 98,304 B
    float* biasf  = (float*)(w + 270630912);     // 131,072 B

    prep_k<<<1152, 256, 0, stream>>>(Wqkv, Wo, te, Wt, bt, btab,
                                     wqkvbf, wobf, qkvt, biasf);
    fused_k<<<1024, 512, 0, stream>>>(x, wqkvbf, bqkv, qkvt, biasf, aoutbf);
    gemm_out_k<<<dim3(4, 512), 256, 0, stream>>>(aoutbf, wobf, bo, out);
}

// Round 3
// 501.147 us; speedup vs baseline: 1.0587x; 1.0103x over previous
//
#include <hip/hip_runtime.h>

using u16 = unsigned short;
typedef __bf16 bf16x8 __attribute__((ext_vector_type(8)));
typedef float floatx4 __attribute__((ext_vector_type(4)));

// ---------- helpers ----------
__device__ __forceinline__ u16 f2bf(float f) {
    union { float f; unsigned u; } v; v.f = f;
    unsigned r = v.u + 0x7fffu + ((v.u >> 16) & 1u);   // RNE
    return (u16)(r >> 16);
}

__device__ __forceinline__ void gld16(const void* g, void* l) {
    __builtin_amdgcn_global_load_lds(
        (const __attribute__((address_space(1))) void*)g,
        (__attribute__((address_space(3))) void*)l, 16, 0, 0);
}

__device__ __forceinline__ void cvt4(const float* __restrict__ src,
                                     u16* __restrict__ dst, int i) {
    float4 v = *(const float4*)(src + i);
    ushort4 o;
    o.x = f2bf(v.x); o.y = f2bf(v.y); o.z = f2bf(v.z); o.w = f2bf(v.w);
    *(ushort4*)(dst + i) = o;
}

// ---------- prep: weight converts + time-qkv + bias expansion ----------
// blocks: [0,768) Wqkv cvt | [768,1024) Wo cvt | [1024,1120) time qkv |
//         [1120,1152) bias_full
__global__ __launch_bounds__(256) void prep_k(
    const float* __restrict__ Wqkv, const float* __restrict__ Wo,
    const float* __restrict__ te, const float* __restrict__ Wt,
    const float* __restrict__ bt, const float* __restrict__ btab,
    u16* __restrict__ wqkvbf, u16* __restrict__ wobf,
    float* __restrict__ qkvt, float* __restrict__ biasf)
{
    const int b = blockIdx.x, tid = threadIdx.x;
    if (b < 768) {
        cvt4(Wqkv, wqkvbf, b * 1024 + tid * 4);
    } else if (b < 1024) {
        cvt4(Wo, wobf, (b - 768) * 1024 + tid * 4);
    } else if (b < 1120) {
        const int bb = b - 1024;
        const int batch = bb / 6;
        const int c = (bb % 6) * 256 + tid;
        const float4* a4 = (const float4*)(te + batch * 512);
        const float4* w4 = (const float4*)(Wt + (size_t)c * 512);
        float s = 0.f;
        for (int i = 0; i < 128; ++i) {
            float4 av = a4[i], wv = w4[i];
            s += av.x * wv.x + av.y * wv.y + av.z * wv.z + av.w * wv.w;
        }
        qkvt[batch * 1536 + c] = s + bt[c];
    } else {
        const int e0 = (b - 1120) * 1024 + tid;
        for (int k = 0; k < 4; ++k) {
            int e = e0 + k * 256;
            int h = e >> 12, rc = e & 4095, row = rc >> 6, col = rc & 63;
            int idx = ((row >> 3) - (col >> 3) + 7) * 15 + ((row & 7) - (col & 7) + 7);
            biasf[e] = btab[idx * 8 + h];
        }
    }
}

// ---------- fused: x-cvt + qkv GEMM + windowed attention ----------
// block = 1 window (64 tokens), 512 threads = 8 waves = 8 heads.
// x window staged once to LDS; per wave: q/k/v 64x64x512 GEMMs with explicit
// 2-deep register double-buffer (prefetch ks+1 during MFMAs of ks) so the
// ~200cy L2 B-frag latency hides under the 16-MFMA cluster. T5 setprio around
// MFMA clusters (waves drift independently after the single barrier).

#define LDAB(AF, BF, KS)                                                       \
  _Pragma("unroll") for (int mt_ = 0; mt_ < 4; ++mt_)                          \
    AF[mt_] = *(const bf16x8*)&xw[(mt_ * 16 + ln) * 520 + (KS) * 32 + quad * 8];\
  _Pragma("unroll") for (int nt_ = 0; nt_ < 4; ++nt_)                          \
    BF[nt_] = *(const bf16x8*)(wb + (size_t)nt_ * 16 * 512 + (KS) * 32);

#define MM8(AF, BF)                                                            \
  __builtin_amdgcn_s_setprio(1);                                               \
  _Pragma("unroll") for (int mt_ = 0; mt_ < 4; ++mt_)                          \
    _Pragma("unroll") for (int nt_ = 0; nt_ < 4; ++nt_)                        \
      acc[mt_][nt_] = __builtin_amdgcn_mfma_f32_16x16x32_bf16(                 \
          AF[mt_], BF[nt_], acc[mt_][nt_], 0, 0, 0);                           \
  __builtin_amdgcn_s_setprio(0);

#define GEMM64(CB)                                                             \
  {                                                                            \
    const u16* wb = wqkv + (size_t)((CB) + ln) * 512 + quad * 8;               \
    _Pragma("unroll") for (int i_ = 0; i_ < 4; ++i_)                           \
      _Pragma("unroll") for (int j_ = 0; j_ < 4; ++j_)                         \
        acc[i_][j_] = (floatx4){0.f, 0.f, 0.f, 0.f};                           \
    bf16x8 aX[4], bX[4], aY[4], bY[4];                                         \
    LDAB(aX, bX, 0);                                                           \
    _Pragma("unroll") for (int ks = 0; ks < 16; ks += 2) {                     \
      if (ks + 1 < 16) { LDAB(aY, bY, ks + 1); }                               \
      MM8(aX, bX);                                                             \
      if (ks + 2 < 16) { LDAB(aX, bX, ks + 2); }                               \
      MM8(aY, bY);                                                             \
    }                                                                          \
  }

// write acc (+bias+time) to buf as [token][d]
#define WRN(CB)                                                                \
  _Pragma("unroll") for (int nt = 0; nt < 4; ++nt) {                           \
    const int col_ = (CB) + nt * 16 + ln;                                      \
    const float add_ = bqkv[col_] + qtv[col_];                                 \
    _Pragma("unroll") for (int mt = 0; mt < 4; ++mt)                           \
      _Pragma("unroll") for (int r = 0; r < 4; ++r)                            \
        buf[(mt * 16 + quad * 4 + r) * 72 + nt * 16 + ln] =                    \
            f2bf(acc[mt][nt][r] + add_);                                       \
  }

// write acc (+bias+time) to buf transposed: [d][token]  (V^T)
#define WRT(CB)                                                                \
  _Pragma("unroll") for (int nt = 0; nt < 4; ++nt) {                           \
    const int col_ = (CB) + nt * 16 + ln;                                      \
    const float add_ = bqkv[col_] + qtv[col_];                                 \
    _Pragma("unroll") for (int mt = 0; mt < 4; ++mt)                           \
      _Pragma("unroll") for (int r = 0; r < 4; ++r)                            \
        buf[(nt * 16 + ln) * 72 + mt * 16 + quad * 4 + r] =                    \
            f2bf(acc[mt][nt][r] + add_);                                       \
  }

// read 4x2 fragments from buf rows [i*16+ln], k-elems quad*8 (+32)
#define RDF(DST)                                                               \
  _Pragma("unroll") for (int i_ = 0; i_ < 4; ++i_) {                           \
    const u16* p_ = &buf[(i_ * 16 + ln) * 72 + quad * 8];                      \
    DST[i_][0] = *(const bf16x8*)p_;                                           \
    DST[i_][1] = *(const bf16x8*)(p_ + 32);                                    \
  }

__global__ __launch_bounds__(512, 2) void fused_k(
    const float* __restrict__ x, const u16* __restrict__ wqkv,
    const float* __restrict__ bqkv, const float* __restrict__ qkvt,
    const float* __restrict__ biasf, u16* __restrict__ aout)
{
    __shared__ __align__(16) u16 xw[64 * 520];       // 66,560 B
    __shared__ __align__(16) u16 sbuf[8][64 * 72];   // 73,728 B
    const int tid = threadIdx.x, lane = tid & 63, wv = tid >> 6;
    const int ln = lane & 15, quad = lane >> 4;
    const int w = blockIdx.x;
    const int bb = w >> 6, nh = (w >> 3) & 7, nw = w & 7;
    const int tbase = bb * 4096 + nh * 512 + nw * 8;  // + wi*64 + wj
    const int h = wv;
    u16* buf = sbuf[wv];
    const float* qtv = qkvt + bb * 1536;

    // ---- stage x window -> bf16 LDS [64][520] ----
    {
        const int t = tid >> 3, cc = tid & 7;
        const int g = tbase + (t >> 3) * 64 + (t & 7);
        const float* xr = x + (size_t)g * 512;
        u16* dst = &xw[t * 520];
#pragma unroll
        for (int c = 0; c < 8; ++c) {
            const int col = cc * 8 + c * 64;
            float4 a = *(const float4*)(xr + col);
            float4 bvec = *(const float4*)(xr + col + 4);
            ushort4 lo, hi;
            lo.x = f2bf(a.x); lo.y = f2bf(a.y); lo.z = f2bf(a.z); lo.w = f2bf(a.w);
            hi.x = f2bf(bvec.x); hi.y = f2bf(bvec.y); hi.z = f2bf(bvec.z); hi.w = f2bf(bvec.w);
            *(ushort4*)(dst + col) = lo;
            *(ushort4*)(dst + col + 4) = hi;
        }
    }
    __syncthreads();   // xw ready; afterwards waves are fully independent

    floatx4 acc[4][4];
    bf16x8 qf[4][2], kf[4][2], vtf[4][2];

    // ---- Q = xw @ Wqkv[h*64..)^T + bqkv + qkvt ----
    GEMM64(h * 64);
    WRN(h * 64);
    RDF(qf);                       // A-frags: rows = q-tokens

    // ---- K ----
    GEMM64(512 + h * 64);
    WRN(512 + h * 64);
    RDF(kf);                       // B-frags: rows = kv-tokens

    // ---- V (transposed store) ----
    GEMM64(1024 + h * 64);
    WRT(1024 + h * 64);
    RDF(vtf);                      // B-frags from V^T rows = d; regs hoisted
                                   // before P overwrites buf below

    // ---- S = Q K^T * scale + bias, softmax, P -> buf (bf16) ----
#pragma unroll
    for (int mt = 0; mt < 4; ++mt) {
        floatx4 s[4];
        __builtin_amdgcn_s_setprio(1);
#pragma unroll
        for (int nt = 0; nt < 4; ++nt) {
            s[nt] = (floatx4){0.f, 0.f, 0.f, 0.f};
            s[nt] = __builtin_amdgcn_mfma_f32_16x16x32_bf16(qf[mt][0], kf[nt][0], s[nt], 0, 0, 0);
            s[nt] = __builtin_amdgcn_mfma_f32_16x16x32_bf16(qf[mt][1], kf[nt][1], s[nt], 0, 0, 0);
        }
        __builtin_amdgcn_s_setprio(0);
        float z[4][4];
        const float* bptr = biasf + h * 4096 + (mt * 16 + quad * 4) * 64 + ln;
#pragma unroll
        for (int nt = 0; nt < 4; ++nt)
#pragma unroll
            for (int r = 0; r < 4; ++r)
                z[nt][r] = s[nt][r] * 0.125f + bptr[r * 64 + nt * 16];
        float pmax[4], prcp[4];
#pragma unroll
        for (int r = 0; r < 4; ++r) {
            float v = fmaxf(fmaxf(z[0][r], z[1][r]), fmaxf(z[2][r], z[3][r]));
            v = fmaxf(v, __shfl_xor(v, 1));
            v = fmaxf(v, __shfl_xor(v, 2));
            v = fmaxf(v, __shfl_xor(v, 4));
            v = fmaxf(v, __shfl_xor(v, 8));
            pmax[r] = v;
        }
#pragma unroll
        for (int nt = 0; nt < 4; ++nt)
#pragma unroll
            for (int r = 0; r < 4; ++r)
                z[nt][r] = __expf(z[nt][r] - pmax[r]);
#pragma unroll
        for (int r = 0; r < 4; ++r) {
            float v = z[0][r] + z[1][r] + z[2][r] + z[3][r];
            v += __shfl_xor(v, 1);
            v += __shfl_xor(v, 2);
            v += __shfl_xor(v, 4);
            v += __shfl_xor(v, 8);
            prcp[r] = __builtin_amdgcn_rcpf(v);
        }
#pragma unroll
        for (int nt = 0; nt < 4; ++nt)
#pragma unroll
            for (int r = 0; r < 4; ++r)
                buf[(mt * 16 + quad * 4 + r) * 72 + nt * 16 + ln] =
                    f2bf(z[nt][r] * prcp[r]);
    }

    // ---- O = P @ V : A-op from buf (P), B-op from vtf regs ----
#pragma unroll
    for (int mt = 0; mt < 4; ++mt) {
        const u16* pr = &buf[(mt * 16 + ln) * 72 + quad * 8];
        const bf16x8 pf0 = *(const bf16x8*)pr;
        const bf16x8 pf1 = *(const bf16x8*)(pr + 32);
#pragma unroll
        for (int dt = 0; dt < 4; ++dt) {
            floatx4 o = (floatx4){0.f, 0.f, 0.f, 0.f};
            __builtin_amdgcn_s_setprio(1);
            o = __builtin_amdgcn_mfma_f32_16x16x32_bf16(pf0, vtf[dt][0], o, 0, 0, 0);
            o = __builtin_amdgcn_mfma_f32_16x16x32_bf16(pf1, vtf[dt][1], o, 0, 0, 0);
            __builtin_amdgcn_s_setprio(0);
            const size_t rbase =
                (size_t)(w * 64 + mt * 16 + quad * 4) * 512 + h * 64 + dt * 16 + ln;
#pragma unroll
            for (int r = 0; r < 4; ++r)
                aout[rbase + (size_t)r * 512] = f2bf(o[r]);
        }
    }
}

// ---------- GEMM2: out = attn @ Wo^T + bo, fp32 out ----------
__global__ __launch_bounds__(256, 3) void gemm_out_k(
    const u16* __restrict__ A, const u16* __restrict__ B,
    const float* __restrict__ bo, float* __restrict__ C)
{
    __shared__ __align__(16) u16 lA[128 * 32];
    __shared__ __align__(16) u16 lB[128 * 32];
    const int tid = threadIdx.x;
    const int lane = tid & 63, wv = tid >> 6;
    const int ln = lane & 15, quad = lane >> 4;
    const int tn = blockIdx.x, tm = blockIdx.y;
    const int wm = (wv & 1) * 64, wn = (wv >> 1) * 64;

    floatx4 acc[4][4];
#pragma unroll
    for (int i = 0; i < 4; ++i)
#pragma unroll
        for (int j = 0; j < 4; ++j) acc[i][j] = (floatx4){0.f, 0.f, 0.f, 0.f};

    const int srow = tid >> 2, scb = tid & 3;
    const u16* ag = A + (size_t)(tm * 128 + srow) * 512 + scb * 8;
    const u16* bg = B + (size_t)(tn * 128 + srow) * 512 + scb * 8;
    u16* la0 = &lA[tid * 8];
    u16* la1 = &lA[2048 + tid * 8];
    u16* lb0 = &lB[tid * 8];
    u16* lb1 = &lB[2048 + tid * 8];

    for (int k0 = 0; k0 < 512; k0 += 32) {
        __syncthreads();
        gld16(ag + k0, la0);
        gld16(ag + 64 * 512 + k0, la1);
        gld16(bg + k0, lb0);
        gld16(bg + 64 * 512 + k0, lb1);
        __syncthreads();
        bf16x8 af[4], bf[4];
#pragma unroll
        for (int mt = 0; mt < 4; ++mt)
            af[mt] = *(const bf16x8*)&lA[(wm + mt * 16 + ln) * 32 + quad * 8];
#pragma unroll
        for (int nt = 0; nt < 4; ++nt)
            bf[nt] = *(const bf16x8*)&lB[(wn + nt * 16 + ln) * 32 + quad * 8];
#pragma unroll
        for (int mt = 0; mt < 4; ++mt)
#pragma unroll
            for (int nt = 0; nt < 4; ++nt)
                acc[mt][nt] = __builtin_amdgcn_mfma_f32_16x16x32_bf16(
                    af[mt], bf[nt], acc[mt][nt], 0, 0, 0);
    }

#pragma unroll
    for (int nt = 0; nt < 4; ++nt) {
        const int col = tn * 128 + wn + nt * 16 + ln;
        const float add = bo[col];
#pragma unroll
        for (int mt = 0; mt < 4; ++mt) {
            const int row0 = tm * 128 + wm + mt * 16 + quad * 4;
#pragma unroll
            for (int r = 0; r < 4; ++r)
                C[(size_t)(row0 + r) * 512 + col] = acc[mt][nt][r] + add;
        }
    }
}

// ---------- launch ----------
extern "C" void kernel_launch(void* const* d_in, const int* in_sizes, int n_in,
                              void* d_out, int out_size, void* d_ws, size_t ws_size,
                              hipStream_t stream)
{
    const float* x    = (const float*)d_in[0];
    const float* te   = (const float*)d_in[1];
    const float* Wqkv = (const float*)d_in[2];
    const float* bqkv = (const float*)d_in[3];
    const float* Wt   = (const float*)d_in[4];
    const float* bt   = (const float*)d_in[5];
    const float* Wo   = (const float*)d_in[6];
    const float* bo   = (const float*)d_in[7];
    const float* btab = (const float*)d_in[8];
    float* out = (float*)d_out;

    char* w = (char*)d_ws;
    u16*   aoutbf = (u16*)(w);                   // attn out: 67,108,864 B
    u16*   wqkvbf = (u16*)(w + 268435456);       // 1,572,864 B
    u16*   wobf   = (u16*)(w + 270008320);       // 524,288 B
    float* qkvt   = (float*)(w + 270532608);     // 98,304 B
    float* biasf  = (float*)(w + 270630912);     // 131,072 B

    prep_k<<<1152, 256, 0, stream>>>(Wqkv, Wo, te, Wt, bt, btab,
                                     wqkvbf, wobf, qkvt, biasf);
    fused_k<<<1024, 512, 0, stream>>>(x, wqkvbf, bqkv, qkvt, biasf, aoutbf);
    gemm_out_k<<<dim3(4, 512), 256, 0, stream>>>(aoutbf, wobf, bo, out);
}